// Round 8
// baseline (168.809 us; speedup 1.0000x reference)
//
#include <hip/hip_runtime.h>
#include <hip/hip_fp16.h>

#define HID 2048
#define FIVEH 10240
#define INP 128
#define BATCH 2048

typedef _Float16 half8 __attribute__((ext_vector_type(8)));
typedef float f32x4 __attribute__((ext_vector_type(4)));

// load 8 consecutive f32, convert to half8 in-register
__device__ __forceinline__ half8 cvt8(const float* p) {
  float4 a = *(const float4*)p;
  float4 b = *(const float4*)(p + 4);
  half8 h;
  h[0] = (_Float16)a.x; h[1] = (_Float16)a.y; h[2] = (_Float16)a.z; h[3] = (_Float16)a.w;
  h[4] = (_Float16)b.x; h[5] = (_Float16)b.y; h[6] = (_Float16)b.z; h[7] = (_Float16)b.w;
  return h;
}

// ---------------- MFMA GEMM (r6-verified): in-register f32->f16 cvt, f16 up out -------
// Wave: 4 m-tiles (64 rows) x 128-col strip, K=128 in 4 MFMA k-steps.
__global__ __launch_bounds__(256) void gemm_up(const float* __restrict__ A,
                                               const float* __restrict__ W,
                                               const float* __restrict__ bias,
                                               _Float16* __restrict__ up16,
                                               int row0, int nrows) {
  int tid = threadIdx.x, wave = tid >> 6, lane = tid & 63;
  int mg_count = nrows >> 6;
  int wid = blockIdx.x * 4 + wave;
  if (wid >= mg_count * 80) return;
  int mg = wid % mg_count;
  int ns = wid / mg_count;
  int nl = lane & 15, quad = lane >> 4;

  half8 af[4][4];
#pragma unroll
  for (int mt = 0; mt < 4; ++mt) {
    const float* arow = A + (size_t)(row0 + mg * 64 + mt * 16 + nl) * INP + quad * 8;
#pragma unroll
    for (int ks = 0; ks < 4; ++ks) af[mt][ks] = cvt8(arow + ks * 32);
  }

#pragma unroll
  for (int nt = 0; nt < 8; ++nt) {
    int ncol = ns * 128 + nt * 16 + nl;
    const float* wrow = W + (size_t)ncol * INP + quad * 8;
    half8 bf[4];
#pragma unroll
    for (int ks = 0; ks < 4; ++ks) bf[ks] = cvt8(wrow + ks * 32);
    float bv = bias[ncol];
#pragma unroll
    for (int mt = 0; mt < 4; ++mt) {
      f32x4 acc = {0.f, 0.f, 0.f, 0.f};
#pragma unroll
      for (int ks = 0; ks < 4; ++ks)
        acc = __builtin_amdgcn_mfma_f32_16x16x32_f16(af[mt][ks], bf[ks], acc, 0, 0, 0);
      int mbase = mg * 64 + mt * 16 + quad * 4;
#pragma unroll
      for (int r = 0; r < 4; ++r)
        up16[(size_t)(mbase + r) * FIVEH + ncol] = (_Float16)(acc[r] + bv);
    }
  }
}

// ---------------- f16-LDS helpers ----------------
__device__ __forceinline__ float2 h2ld(const __half2* p, int i) {
  return __half22float2(p[i]);
}
__device__ __forceinline__ void h2st(__half2* p, int i, float x, float y) {
  p[i] = __floats2half2_rn(x, y);
}

// ---------------- radix-4 Stockham FFT on __half2 LDS (structure verified r7) ---------
// N=2048 = 2 * 4^5: radix-2 (L=1) then radix-4 with L=2,8,32,128,512.
// sgn = -1 forward, +1 inverse (unscaled). 6 swaps -> result back in entry src.
__device__ __forceinline__ void fft_r4(__half2*& src, __half2*& dst, int tid, float sgn) {
#pragma unroll
  for (int t = 0; t < 4; ++t) {
    int i = tid + (t << 8);
    float2 a = h2ld(src, i), b = h2ld(src, i + 1024);
    h2st(dst, 2 * i,     a.x + b.x, a.y + b.y);
    h2st(dst, 2 * i + 1, a.x - b.x, a.y - b.y);
  }
  __syncthreads();
  { __half2* t = src; src = dst; dst = t; }

#pragma unroll
  for (int pass = 0; pass < 5; ++pass) {
    const int L = 2 << (2 * pass);            // 2,8,32,128,512
    const float co = sgn * 1.5707963267948966f / (float)L;   // sgn*pi/(2L)
#pragma unroll
    for (int t = 0; t < 2; ++t) {
      int i = tid + (t << 8);
      int k = i & (L - 1);
      int base4 = ((i - k) << 2) + k;         // 4*m*L + k
      float2 x0 = h2ld(src, i),        x1 = h2ld(src, i + 512);
      float2 x2 = h2ld(src, i + 1024), x3 = h2ld(src, i + 1536);
      float ang = co * (float)k;
      float s1, c1; __sincosf(ang, &s1, &c1);
      float c2 = c1 * c1 - s1 * s1, s2 = 2.f * c1 * s1;
      float c3 = c1 * c2 - s1 * s2, s3 = c1 * s2 + s1 * c2;
      float y1r = x1.x * c1 - x1.y * s1, y1i = x1.x * s1 + x1.y * c1;
      float y2r = x2.x * c2 - x2.y * s2, y2i = x2.x * s2 + x2.y * c2;
      float y3r = x3.x * c3 - x3.y * s3, y3i = x3.x * s3 + x3.y * c3;
      float t0r = x0.x + y2r, t0i = x0.y + y2i;
      float t1r = x0.x - y2r, t1i = x0.y - y2i;
      float t2r = y1r + y3r, t2i = y1i + y3i;
      float t3r = y1r - y3r, t3i = y1i - y3i;
      h2st(dst, base4,         t0r + t2r, t0i + t2i);
      h2st(dst, base4 + 2 * L, t0r - t2r, t0i - t2i);
      h2st(dst, base4 + L,     t1r - sgn * t3i, t1i + sgn * t3r);
      h2st(dst, base4 + 3 * L, t1r + sgn * t3i, t1i - sgn * t3r);
    }
    __syncthreads();
    { __half2* t = src; src = dst; dst = t; }
  }
}

// wave shfl reduce + tiny LDS combine
__device__ __forceinline__ void block_reduce2(float& pr, float& pi,
                                              float* redr, float* redi, int tid) {
  for (int off = 32; off > 0; off >>= 1) {
    pr += __shfl_down(pr, off, 64);
    pi += __shfl_down(pi, off, 64);
  }
  if ((tid & 63) == 0) { redr[tid >> 6] = pr; redi[tid >> 6] = pi; }
  __syncthreads();
  pr = redr[0] + redr[1] + redr[2] + redr[3];
  pi = redi[0] + redi[1] + redi[2] + redi[3];
  __syncthreads();
}

// omode: 0 interleaved, 1 planar (verified r5), 2 real-only
// invN folded at the PERMUTE step (before IFFT) to keep f16 LDS in range:
// post-HH1 values ~4e3 (f16 ok); unscaled IFFT would hit ~4e5 (overflow) -> scale first.
#define ROW_PIPELINE(UP)                                                        \
  __half2 *ca = sA, *cb = sB;                                                   \
  fft_r4(ca, cb, tid, -1.0f);                                                   \
  float cc[8], ss[8];                                                           \
  {                                                                             \
    float pr = 0.f, pi = 0.f;                                                   \
    _Pragma("unroll") for (int e = 0; e < 8; ++e) {                             \
      int k = tid + (e << 8);                                                   \
      float sv, cv; __sincosf(UP(e, 3), &sv, &cv);                              \
      cc[e] = cv; ss[e] = sv;                                                   \
      float2 h = h2ld(ca, k);                                                   \
      pr += cv * h.x + sv * h.y;                                                \
      pi += cv * h.y - sv * h.x;                                                \
    }                                                                           \
    block_reduce2(pr, pi, redr, redi, tid);                                     \
    _Pragma("unroll") for (int e = 0; e < 8; ++e) {                             \
      int k = tid + (e << 8);                                                   \
      float2 h = h2ld(ca, k);                                                   \
      h2st(ca, k, h.x - 2.f * (cc[e] * pr - ss[e] * pi),                        \
                  h.y - 2.f * (cc[e] * pi + ss[e] * pr));                       \
    }                                                                           \
  }                                                                             \
  __syncthreads();                                                              \
  const float invN = 1.0f / (float)HID;                                         \
  _Pragma("unroll") for (int e = 0; e < 8; ++e) {                               \
    int k = tid + (e << 8);                                                     \
    float sv, cv; __sincosf(UP(e, 1), &sv, &cv);                                \
    float2 h = h2ld(ca, perm[k]);                                               \
    h2st(cb, k, (cv * h.x - sv * h.y) * invN, (cv * h.y + sv * h.x) * invN);    \
  }                                                                             \
  __syncthreads();                                                              \
  { __half2* t = ca; ca = cb; cb = t; }                                         \
  fft_r4(ca, cb, tid, 1.0f);                                                    \
  float prj_r, prj_i;                                                           \
  {                                                                             \
    float pr = 0.f, pi = 0.f;                                                   \
    _Pragma("unroll") for (int e = 0; e < 8; ++e) {                             \
      int k = tid + (e << 8);                                                   \
      float sv, cv; __sincosf(UP(e, 4), &sv, &cv);                              \
      cc[e] = cv; ss[e] = sv;                                                   \
      float2 h = h2ld(ca, k);                                                   \
      pr += cv * h.x + sv * h.y;                                                \
      pi += cv * h.y - sv * h.x;                                                \
    }                                                                           \
    block_reduce2(pr, pi, redr, redi, tid);                                     \
    prj_r = pr; prj_i = pi;                                                     \
  }                                                                             \
  _Pragma("unroll") for (int e = 0; e < 8; ++e) {                               \
    int k = tid + (e << 8);                                                     \
    float2 h = h2ld(ca, k);                                                     \
    float hr = h.x - 2.f * (cc[e] * prj_r - ss[e] * prj_i);                     \
    float hi = h.y - 2.f * (cc[e] * prj_i + ss[e] * prj_r);                     \
    float s3, c3; __sincosf(UP(e, 2), &s3, &c3);                                \
    float zr = c3 * hr - s3 * hi;                                               \
    float zi = c3 * hi + s3 * hr;                                               \
    float mag = sqrtf(zr * zr + zi * zi);                                       \
    float nm = mag + beta[k];                                                   \
    nm = nm > 0.f ? nm : 0.f;                                                   \
    float orr, oii;                                                             \
    if (mag > 0.f) { float sc = nm / mag; orr = zr * sc; oii = zi * sc; }       \
    else { orr = nm; oii = 0.f; }                                               \
    long m = (long)b * HID + k;                                                 \
    if (omode == 1) {                                                           \
      const long half = (long)BATCH * HID;                                      \
      if (half + m < out_size_l) { out[m] = orr; out[half + m] = oii; }         \
    } else if (omode == 0) {                                                    \
      if (2 * m + 1 < out_size_l) {                                             \
        float2 o; o.x = orr; o.y = oii;                                         \
        *(float2*)(out + 2 * m) = o;                                            \
      }                                                                         \
    } else {                                                                    \
      if (m < out_size_l) out[m] = orr;                                         \
    }                                                                           \
  }

// ---------------- row kernel: f16 LDS ping-pong -> ~16.4KB -> 8 blocks/CU -------------
__global__ __launch_bounds__(256, 8) void urnn_row(const _Float16* __restrict__ up16,
                                                   const float* __restrict__ hxr,
                                                   const float* __restrict__ hxi,
                                                   const float* __restrict__ beta,
                                                   const int* __restrict__ perm,
                                                   float* __restrict__ out,
                                                   int row0, long out_size_l, int omode) {
  __shared__ __half2 sA[HID], sB[HID];
  __shared__ float redr[4], redi[4];

  int tid = threadIdx.x;
  int b = row0 + blockIdx.x;
  const _Float16* uprow = up16 + (size_t)blockIdx.x * FIVEH;
#define UPG(e, s) ((float)uprow[(s) * HID + tid + ((e) << 8)])

#pragma unroll
  for (int e = 0; e < 8; ++e) {
    int k = tid + (e << 8);
    float sv, cv; __sincosf(UPG(e, 0), &sv, &cv);
    float hr = hxr[(size_t)b * HID + k];
    float hi = hxi[(size_t)b * HID + k];
    h2st(sA, k, cv * hr - sv * hi, cv * hi + sv * hr);
  }
  __syncthreads();
  ROW_PIPELINE(UPG)
#undef UPG
}

// ---------------- ws-free fused fallback (f32-exact per-thread GEMM) ------------------
__global__ __launch_bounds__(256) void urnn_fused(const float* __restrict__ A,
                                                  const float* __restrict__ W,
                                                  const float* __restrict__ bias,
                                                  const float* __restrict__ hxr,
                                                  const float* __restrict__ hxi,
                                                  const float* __restrict__ beta,
                                                  const int* __restrict__ perm,
                                                  float* __restrict__ out,
                                                  long out_size_l, int omode) {
  __shared__ __half2 sA[HID], sB[HID];
  __shared__ float redr[4], redi[4];
  __shared__ float4 xs4[INP / 4];

  int tid = threadIdx.x;
  int b = blockIdx.x;

  if (tid < INP / 4) xs4[tid] = ((const float4*)(A + (size_t)b * INP))[tid];
  __syncthreads();

  float upreg[40];
#pragma unroll
  for (int se = 0; se < 40; ++se) {
    int n = ((se >> 3) << 11) + ((se & 7) << 8) + tid;
    upreg[se] = bias[n];
  }
  for (int kb = 0; kb < 4; ++kb) {
    float4 xv[8];
#pragma unroll
    for (int j = 0; j < 8; ++j) xv[j] = xs4[kb * 8 + j];
#pragma unroll
    for (int se = 0; se < 40; ++se) {
      int n = ((se >> 3) << 11) + ((se & 7) << 8) + tid;
      const float4* wr = (const float4*)(W + (size_t)n * INP + (kb << 5));
      float a = 0.f;
#pragma unroll
      for (int j = 0; j < 8; ++j) {
        float4 wv = wr[j];
        a += xv[j].x * wv.x + xv[j].y * wv.y + xv[j].z * wv.z + xv[j].w * wv.w;
      }
      upreg[se] += a;
    }
  }
#define UPR(e, s) (upreg[(s) * 8 + (e)])
#pragma unroll
  for (int e = 0; e < 8; ++e) {
    int k = tid + (e << 8);
    float sv, cv; __sincosf(UPR(e, 0), &sv, &cv);
    float hr = hxr[(size_t)b * HID + k];
    float hi = hxi[(size_t)b * HID + k];
    h2st(sA, k, cv * hr - sv * hi, cv * hi + sv * hr);
  }
  __syncthreads();
  ROW_PIPELINE(UPR)
#undef UPR
}

extern "C" void kernel_launch(void* const* d_in, const int* in_sizes, int n_in,
                              void* d_out, int out_size, void* d_ws, size_t ws_size,
                              hipStream_t stream) {
  const float* input   = (const float*)d_in[0];
  const float* hx_real = (const float*)d_in[1];
  const float* hx_imag = (const float*)d_in[2];
  const float* W       = (const float*)d_in[3];
  const float* bvec    = (const float*)d_in[4];
  const float* beta    = (const float*)d_in[5];
  const int*   perm    = (const int*)d_in[6];

  int omode;
  if (out_size == BATCH * HID) omode = 2;
  else if (out_size == 2 * BATCH * HID) omode = 1;
  else omode = 0;

  // no fixed staging: ws holds only the f16 up chunk (20480 B/row).
  // ws >= 41.94MB (established r5/r7) -> chunk = 2048: ONE gemm + ONE row dispatch.
  const size_t rowbytes = (size_t)FIVEH * sizeof(_Float16);
  long chunk = (long)(ws_size / rowbytes);
  if (chunk > BATCH) chunk = BATCH;
  chunk &= ~63L;

  if (chunk >= 64) {
    _Float16* up16 = (_Float16*)d_ws;
    for (long row0 = 0; row0 < BATCH; row0 += chunk) {
      int rows = (int)((row0 + chunk <= BATCH) ? chunk : (BATCH - row0));
      int waves = (rows >> 6) * 80;
      gemm_up<<<(waves + 3) / 4, 256, 0, stream>>>(input, W, bvec, up16, (int)row0, rows);
      urnn_row<<<rows, 256, 0, stream>>>(up16, hx_real, hx_imag, beta, perm,
                                         (float*)d_out, (int)row0, (long)out_size, omode);
    }
  } else {
    urnn_fused<<<BATCH, 256, 0, stream>>>(input, W, bvec, hx_real, hx_imag, beta, perm,
                                          (float*)d_out, (long)out_size, omode);
  }
}

// Round 9
// 155.050 us; speedup vs baseline: 1.0887x; 1.0887x over previous
//
#include <hip/hip_runtime.h>
#include <hip/hip_fp16.h>

#define HID 2048
#define FIVEH 10240
#define INP 128
#define BATCH 2048

typedef _Float16 half8 __attribute__((ext_vector_type(8)));
typedef float f32x4 __attribute__((ext_vector_type(4)));

// load 8 consecutive f32, convert to half8 in-register
__device__ __forceinline__ half8 cvt8(const float* p) {
  float4 a = *(const float4*)p;
  float4 b = *(const float4*)(p + 4);
  half8 h;
  h[0] = (_Float16)a.x; h[1] = (_Float16)a.y; h[2] = (_Float16)a.z; h[3] = (_Float16)a.w;
  h[4] = (_Float16)b.x; h[5] = (_Float16)b.y; h[6] = (_Float16)b.z; h[7] = (_Float16)b.w;
  return h;
}

// ---------------- GEMM v3: LDS-staged W, LDS-transposed coalesced epilogue ------------
// Block: 128 rows x 128 cols, 4 waves (each 32 rows x 128 cols, 64 MFMA).
// LDS tile stride 136 f16 (=272B): +16B pad so 256B-stride frag reads are conflict-free.
#define WSTRIDE 136
__global__ __launch_bounds__(256) void gemm_up(const float* __restrict__ A,
                                               const float* __restrict__ W,
                                               const float* __restrict__ bias,
                                               _Float16* __restrict__ up16,
                                               int row0, int nrows) {
  __shared__ _Float16 Ws[128 * WSTRIDE];   // [col][k] staging, reused as [row][col] tile
  int tid = threadIdx.x, wave = tid >> 6, lane = tid & 63;
  int bx = blockIdx.x;                      // col strip: cols bx*128 ..
  int by = blockIdx.y;                      // row group: rows by*128 .. (local to chunk)
  int nl = lane & 15, quad = lane >> 4;

  // stage W strip (128 cols x 128 k) f32 -> f16, coalesced reads, b128 LDS writes
  {
    const float* src = W + (size_t)(bx * 128) * INP;
#pragma unroll
    for (int it = 0; it < 8; ++it) {
      int n = (it * 256 + tid) * 8;         // 8 consecutive elems, same col (8 | 128)
      int col = n >> 7, k = n & 127;
      *(half8*)(Ws + col * WSTRIDE + k) = cvt8(src + n);
    }
  }

  // A fragments straight from global (f32 -> f16 in-register)
  half8 af[2][4];
  int rowbase = row0 + by * 128 + wave * 32;
#pragma unroll
  for (int mt = 0; mt < 2; ++mt) {
    const float* ar = A + (size_t)(rowbase + mt * 16 + nl) * INP + quad * 8;
#pragma unroll
    for (int ks = 0; ks < 4; ++ks) af[mt][ks] = cvt8(ar + ks * 32);
  }
  __syncthreads();

  f32x4 acc[2][8];
#pragma unroll
  for (int nt = 0; nt < 8; ++nt) {
    half8 bf[4];
#pragma unroll
    for (int ks = 0; ks < 4; ++ks)
      bf[ks] = *(const half8*)(Ws + (nt * 16 + nl) * WSTRIDE + quad * 8 + ks * 32);
#pragma unroll
    for (int mt = 0; mt < 2; ++mt) {
      f32x4 a = {0.f, 0.f, 0.f, 0.f};
#pragma unroll
      for (int ks = 0; ks < 4; ++ks)
        a = __builtin_amdgcn_mfma_f32_16x16x32_f16(af[mt][ks], bf[ks], a, 0, 0, 0);
      acc[mt][nt] = a;
    }
  }
  __syncthreads();   // all waves done reading Ws

  // write acc(+bias) into LDS tile [row][col], row = wave*32+mt*16+quad*4+r, col = nt*16+nl
#pragma unroll
  for (int nt = 0; nt < 8; ++nt) {
    float bv = bias[bx * 128 + nt * 16 + nl];
#pragma unroll
    for (int mt = 0; mt < 2; ++mt) {
      int rl = wave * 32 + mt * 16 + quad * 4;
#pragma unroll
      for (int r = 0; r < 4; ++r)
        Ws[(rl + r) * WSTRIDE + nt * 16 + nl] = (_Float16)(acc[mt][nt][r] + bv);
    }
  }
  __syncthreads();

  // coalesced store: each 16B chunk of the 128x128 f16 tile -> up16 row-major
#pragma unroll
  for (int it = 0; it < 8; ++it) {
    int v = it * 256 + tid;                 // 2048 chunks of 8 f16
    int r = v >> 4, c8 = (v & 15) * 8;
    *(half8*)(up16 + (size_t)(by * 128 + r) * FIVEH + bx * 128 + c8) =
        *(const half8*)(Ws + r * WSTRIDE + c8);
  }
}

// ---------------- f16-LDS helpers ----------------
__device__ __forceinline__ float2 h2ld(const __half2* p, int i) {
  return __half22float2(p[i]);
}
__device__ __forceinline__ void h2st(__half2* p, int i, float x, float y) {
  p[i] = __floats2half2_rn(x, y);
}

// ---------------- radix-4 Stockham FFT on __half2 LDS (verified r7/r8) ----------------
__device__ __forceinline__ void fft_r4(__half2*& src, __half2*& dst, int tid, float sgn) {
#pragma unroll
  for (int t = 0; t < 4; ++t) {
    int i = tid + (t << 8);
    float2 a = h2ld(src, i), b = h2ld(src, i + 1024);
    h2st(dst, 2 * i,     a.x + b.x, a.y + b.y);
    h2st(dst, 2 * i + 1, a.x - b.x, a.y - b.y);
  }
  __syncthreads();
  { __half2* t = src; src = dst; dst = t; }

#pragma unroll
  for (int pass = 0; pass < 5; ++pass) {
    const int L = 2 << (2 * pass);            // 2,8,32,128,512
    const float co = sgn * 1.5707963267948966f / (float)L;
#pragma unroll
    for (int t = 0; t < 2; ++t) {
      int i = tid + (t << 8);
      int k = i & (L - 1);
      int base4 = ((i - k) << 2) + k;
      float2 x0 = h2ld(src, i),        x1 = h2ld(src, i + 512);
      float2 x2 = h2ld(src, i + 1024), x3 = h2ld(src, i + 1536);
      float ang = co * (float)k;
      float s1, c1; __sincosf(ang, &s1, &c1);
      float c2 = c1 * c1 - s1 * s1, s2 = 2.f * c1 * s1;
      float c3 = c1 * c2 - s1 * s2, s3 = c1 * s2 + s1 * c2;
      float y1r = x1.x * c1 - x1.y * s1, y1i = x1.x * s1 + x1.y * c1;
      float y2r = x2.x * c2 - x2.y * s2, y2i = x2.x * s2 + x2.y * c2;
      float y3r = x3.x * c3 - x3.y * s3, y3i = x3.x * s3 + x3.y * c3;
      float t0r = x0.x + y2r, t0i = x0.y + y2i;
      float t1r = x0.x - y2r, t1i = x0.y - y2i;
      float t2r = y1r + y3r, t2i = y1i + y3i;
      float t3r = y1r - y3r, t3i = y1i - y3i;
      h2st(dst, base4,         t0r + t2r, t0i + t2i);
      h2st(dst, base4 + 2 * L, t0r - t2r, t0i - t2i);
      h2st(dst, base4 + L,     t1r - sgn * t3i, t1i + sgn * t3r);
      h2st(dst, base4 + 3 * L, t1r + sgn * t3i, t1i - sgn * t3r);
    }
    __syncthreads();
    { __half2* t = src; src = dst; dst = t; }
  }
}

// wave shfl reduce + tiny LDS combine
__device__ __forceinline__ void block_reduce2(float& pr, float& pi,
                                              float* redr, float* redi, int tid) {
  for (int off = 32; off > 0; off >>= 1) {
    pr += __shfl_down(pr, off, 64);
    pi += __shfl_down(pi, off, 64);
  }
  if ((tid & 63) == 0) { redr[tid >> 6] = pr; redi[tid >> 6] = pi; }
  __syncthreads();
  pr = redr[0] + redr[1] + redr[2] + redr[3];
  pi = redi[0] + redi[1] + redi[2] + redi[3];
  __syncthreads();
}

// omode: 0 interleaved, 1 planar (verified r5), 2 real-only
// invN folded at the permute step (before IFFT) to keep f16 LDS in range.
#define ROW_PIPELINE(UP)                                                        \
  __half2 *ca = sA, *cb = sB;                                                   \
  fft_r4(ca, cb, tid, -1.0f);                                                   \
  float cc[8], ss[8];                                                           \
  {                                                                             \
    float pr = 0.f, pi = 0.f;                                                   \
    _Pragma("unroll") for (int e = 0; e < 8; ++e) {                             \
      int k = tid + (e << 8);                                                   \
      float sv, cv; __sincosf(UP(e, 3), &sv, &cv);                              \
      cc[e] = cv; ss[e] = sv;                                                   \
      float2 h = h2ld(ca, k);                                                   \
      pr += cv * h.x + sv * h.y;                                                \
      pi += cv * h.y - sv * h.x;                                                \
    }                                                                           \
    block_reduce2(pr, pi, redr, redi, tid);                                     \
    _Pragma("unroll") for (int e = 0; e < 8; ++e) {                             \
      int k = tid + (e << 8);                                                   \
      float2 h = h2ld(ca, k);                                                   \
      h2st(ca, k, h.x - 2.f * (cc[e] * pr - ss[e] * pi),                        \
                  h.y - 2.f * (cc[e] * pi + ss[e] * pr));                       \
    }                                                                           \
  }                                                                             \
  __syncthreads();                                                              \
  const float invN = 1.0f / (float)HID;                                         \
  _Pragma("unroll") for (int e = 0; e < 8; ++e) {                               \
    int k = tid + (e << 8);                                                     \
    float sv, cv; __sincosf(UP(e, 1), &sv, &cv);                                \
    float2 h = h2ld(ca, perm[k]);                                               \
    h2st(cb, k, (cv * h.x - sv * h.y) * invN, (cv * h.y + sv * h.x) * invN);    \
  }                                                                             \
  __syncthreads();                                                              \
  { __half2* t = ca; ca = cb; cb = t; }                                         \
  fft_r4(ca, cb, tid, 1.0f);                                                    \
  float prj_r, prj_i;                                                           \
  {                                                                             \
    float pr = 0.f, pi = 0.f;                                                   \
    _Pragma("unroll") for (int e = 0; e < 8; ++e) {                             \
      int k = tid + (e << 8);                                                   \
      float sv, cv; __sincosf(UP(e, 4), &sv, &cv);                              \
      cc[e] = cv; ss[e] = sv;                                                   \
      float2 h = h2ld(ca, k);                                                   \
      pr += cv * h.x + sv * h.y;                                                \
      pi += cv * h.y - sv * h.x;                                                \
    }                                                                           \
    block_reduce2(pr, pi, redr, redi, tid);                                     \
    prj_r = pr; prj_i = pi;                                                     \
  }                                                                             \
  _Pragma("unroll") for (int e = 0; e < 8; ++e) {                               \
    int k = tid + (e << 8);                                                     \
    float2 h = h2ld(ca, k);                                                     \
    float hr = h.x - 2.f * (cc[e] * prj_r - ss[e] * prj_i);                     \
    float hi = h.y - 2.f * (cc[e] * prj_i + ss[e] * prj_r);                     \
    float s3, c3; __sincosf(UP(e, 2), &s3, &c3);                                \
    float zr = c3 * hr - s3 * hi;                                               \
    float zi = c3 * hi + s3 * hr;                                               \
    float mag = sqrtf(zr * zr + zi * zi);                                       \
    float nm = mag + beta[k];                                                   \
    nm = nm > 0.f ? nm : 0.f;                                                   \
    float orr, oii;                                                             \
    if (mag > 0.f) { float sc = nm / mag; orr = zr * sc; oii = zi * sc; }       \
    else { orr = nm; oii = 0.f; }                                               \
    long m = (long)b * HID + k;                                                 \
    if (omode == 1) {                                                           \
      const long half = (long)BATCH * HID;                                      \
      if (half + m < out_size_l) { out[m] = orr; out[half + m] = oii; }         \
    } else if (omode == 0) {                                                    \
      if (2 * m + 1 < out_size_l) {                                             \
        float2 o; o.x = orr; o.y = oii;                                         \
        *(float2*)(out + 2 * m) = o;                                            \
      }                                                                         \
    } else {                                                                    \
      if (m < out_size_l) out[m] = orr;                                         \
    }                                                                           \
  }

// ---------------- row kernel: f16 LDS ping-pong (r8, passed) ----------------
__global__ __launch_bounds__(256, 8) void urnn_row(const _Float16* __restrict__ up16,
                                                   const float* __restrict__ hxr,
                                                   const float* __restrict__ hxi,
                                                   const float* __restrict__ beta,
                                                   const int* __restrict__ perm,
                                                   float* __restrict__ out,
                                                   int row0, long out_size_l, int omode) {
  __shared__ __half2 sA[HID], sB[HID];
  __shared__ float redr[4], redi[4];

  int tid = threadIdx.x;
  int b = row0 + blockIdx.x;
  const _Float16* uprow = up16 + (size_t)blockIdx.x * FIVEH;
#define UPG(e, s) ((float)uprow[(s) * HID + tid + ((e) << 8)])

#pragma unroll
  for (int e = 0; e < 8; ++e) {
    int k = tid + (e << 8);
    float sv, cv; __sincosf(UPG(e, 0), &sv, &cv);
    float hr = hxr[(size_t)b * HID + k];
    float hi = hxi[(size_t)b * HID + k];
    h2st(sA, k, cv * hr - sv * hi, cv * hi + sv * hr);
  }
  __syncthreads();
  ROW_PIPELINE(UPG)
#undef UPG
}

// ---------------- ws-free fused fallback (f32-exact per-thread GEMM) ------------------
__global__ __launch_bounds__(256) void urnn_fused(const float* __restrict__ A,
                                                  const float* __restrict__ W,
                                                  const float* __restrict__ bias,
                                                  const float* __restrict__ hxr,
                                                  const float* __restrict__ hxi,
                                                  const float* __restrict__ beta,
                                                  const int* __restrict__ perm,
                                                  float* __restrict__ out,
                                                  long out_size_l, int omode) {
  __shared__ __half2 sA[HID], sB[HID];
  __shared__ float redr[4], redi[4];
  __shared__ float4 xs4[INP / 4];

  int tid = threadIdx.x;
  int b = blockIdx.x;

  if (tid < INP / 4) xs4[tid] = ((const float4*)(A + (size_t)b * INP))[tid];
  __syncthreads();

  float upreg[40];
#pragma unroll
  for (int se = 0; se < 40; ++se) {
    int n = ((se >> 3) << 11) + ((se & 7) << 8) + tid;
    upreg[se] = bias[n];
  }
  for (int kb = 0; kb < 4; ++kb) {
    float4 xv[8];
#pragma unroll
    for (int j = 0; j < 8; ++j) xv[j] = xs4[kb * 8 + j];
#pragma unroll
    for (int se = 0; se < 40; ++se) {
      int n = ((se >> 3) << 11) + ((se & 7) << 8) + tid;
      const float4* wr = (const float4*)(W + (size_t)n * INP + (kb << 5));
      float a = 0.f;
#pragma unroll
      for (int j = 0; j < 8; ++j) {
        float4 wv = wr[j];
        a += xv[j].x * wv.x + xv[j].y * wv.y + xv[j].z * wv.z + xv[j].w * wv.w;
      }
      upreg[se] += a;
    }
  }
#define UPR(e, s) (upreg[(s) * 8 + (e)])
#pragma unroll
  for (int e = 0; e < 8; ++e) {
    int k = tid + (e << 8);
    float sv, cv; __sincosf(UPR(e, 0), &sv, &cv);
    float hr = hxr[(size_t)b * HID + k];
    float hi = hxi[(size_t)b * HID + k];
    h2st(sA, k, cv * hr - sv * hi, cv * hi + sv * hr);
  }
  __syncthreads();
  ROW_PIPELINE(UPR)
#undef UPR
}

extern "C" void kernel_launch(void* const* d_in, const int* in_sizes, int n_in,
                              void* d_out, int out_size, void* d_ws, size_t ws_size,
                              hipStream_t stream) {
  const float* input   = (const float*)d_in[0];
  const float* hx_real = (const float*)d_in[1];
  const float* hx_imag = (const float*)d_in[2];
  const float* W       = (const float*)d_in[3];
  const float* bvec    = (const float*)d_in[4];
  const float* beta    = (const float*)d_in[5];
  const int*   perm    = (const int*)d_in[6];

  int omode;
  if (out_size == BATCH * HID) omode = 2;
  else if (out_size == 2 * BATCH * HID) omode = 1;
  else omode = 0;

  // ws holds only the f16 up chunk (20480 B/row); ws >= 41.94MB -> single 2048-row shot
  const size_t rowbytes = (size_t)FIVEH * sizeof(_Float16);
  long chunk = (long)(ws_size / rowbytes);
  if (chunk > BATCH) chunk = BATCH;
  chunk &= ~127L;               // gemm block tile = 128 rows

  if (chunk >= 128) {
    _Float16* up16 = (_Float16*)d_ws;
    for (long row0 = 0; row0 < BATCH; row0 += chunk) {
      int rows = (int)((row0 + chunk <= BATCH) ? chunk : (BATCH - row0));
      dim3 g(FIVEH / 128, rows / 128);
      gemm_up<<<g, 256, 0, stream>>>(input, W, bvec, up16, (int)row0, rows);
      urnn_row<<<rows, 256, 0, stream>>>(up16, hx_real, hx_imag, beta, perm,
                                         (float*)d_out, (int)row0, (long)out_size, omode);
    }
  } else {
    urnn_fused<<<BATCH, 256, 0, stream>>>(input, W, bvec, hx_real, hx_imag, beta, perm,
                                          (float*)d_out, (long)out_size, omode);
  }
}